// Round 11
// baseline (478.021 us; speedup 1.0000x reference)
//
#include <hip/hip_runtime.h>

// DiffSSM: B=8, L=2048, D=1024, N=64
#define Bq 8
#define Lq 2048
#define Dq 1024
#define LPq 2050  // L + 2 pad rows

typedef unsigned short u16;
typedef __attribute__((ext_vector_type(8))) short bf16x8;
typedef __attribute__((ext_vector_type(16))) float f32x16;

__device__ __forceinline__ u16 f2bf(float f) {
  unsigned u = __float_as_uint(f);
  u += 0x7FFFu + ((u >> 16) & 1u);   // RNE
  return (u16)(u >> 16);
}
__device__ __forceinline__ float bf2f(u16 s) {
  return __uint_as_float(((unsigned)s) << 16);
}
__device__ __forceinline__ void gld16(const u16* g, u16* l) {
  __builtin_amdgcn_global_load_lds((const __attribute__((address_space(1))) void*)g,
                                   (__attribute__((address_space(3))) void*)l, 16, 0, 0);
}

// ---------------- prep ----------------

// blocks 0-7: kf/kb (2048); blocks 8-39: ns (8192); blocks 40-167: zero pads
__global__ __launch_bounds__(256) void prep_small(
    const float* __restrict__ t,
    const float* __restrict__ Af, const float* __restrict__ Bf, const float* __restrict__ Cf, const float* __restrict__ Df,
    const float* __restrict__ Ab, const float* __restrict__ Bb, const float* __restrict__ Cb, const float* __restrict__ Db,
    float* __restrict__ kf, float* __restrict__ kb,
    float* __restrict__ ns,
    u16* __restrict__ hpad, u16* __restrict__ copad) {
  int tid = blockIdx.x * 256 + threadIdx.x;
  if (blockIdx.x < 8) {
    int l = tid;
    float sf = Df[0], sb = Db[0];
    for (int n = 0; n < 64; n++) {
      sf += __expf((float)l * Af[n * 64 + n]) * (Bf[n] * Cf[n]);
      sb += __expf((float)l * Ab[n * 64 + n]) * (Bb[n] * Cb[n]);
    }
    kf[l] = sf; kb[l] = sb;
  } else if (blockIdx.x < 40) {
    int i = tid - 2048;                 // [0, 8192)
    int b = i >> 10, d = i & 1023;
    float tb = t[b];
    float e;
    if (d < 512) {
      float f = __expf((float)d * (-logf(10000.f) / 511.f));
      e = sinf(tb * f);
    } else {
      float f = __expf((float)(d - 512) * (-logf(10000.f) / 511.f));
      e = cosf(tb * f);
    }
    ns[i] = 1.f / (1.f + __expf(-e));
  } else {
    int i = tid - 10240;                // [0, 32768)
    if (i < 32768) {
      int d = i & 1023;
      int j = i >> 10;                  // [0,32)
      int arr = j & 1, r = (j >> 1) & 1, b = j >> 2;
      size_t off = (size_t)b * LPq * Dq + (r ? (size_t)(LPq - 1) * Dq : 0) + d;
      if (arr == 0) hpad[off] = 0;
      else          copad[off] = 0;
    }
  }
}

// mega prep: [0,8192) cast_x | [8192,8448) trans_w Wi | [8448,8704) trans_w Wo |
// [8704,11776) trans_w3 w1 | [11776,14848) trans_w3 w2 |
// [14848,18944) T-fill: T[t][j] = b1*(t>=j?kf[t-j]:0) + b2*(j>=t?kb[j-t]:0)
__global__ __launch_bounds__(256) void mega_prep(
    const float* __restrict__ x, u16* __restrict__ xb,
    const float* __restrict__ Wi, u16* __restrict__ wit,
    const float* __restrict__ Wo, u16* __restrict__ wot,
    const float* __restrict__ w1, u16* __restrict__ w1t,
    const float* __restrict__ w2, u16* __restrict__ w2t,
    const float* __restrict__ kf, const float* __restrict__ kb,
    const float* __restrict__ be1, const float* __restrict__ be2,
    u16* __restrict__ Tm) {
  int bid = blockIdx.x, tid = threadIdx.x;
  if (bid < 8192) {
    size_t i = ((size_t)bid * 256 + tid) * 8;
    float4 a = *(const float4*)(x + i);
    float4 b = *(const float4*)(x + i + 4);
    u16 o[8] = {f2bf(a.x), f2bf(a.y), f2bf(a.z), f2bf(a.w),
                f2bf(b.x), f2bf(b.y), f2bf(b.z), f2bf(b.w)};
    *(bf16x8*)(xb + i) = *(const bf16x8*)o;
  } else if (bid < 8704) {
    __shared__ float tile[64][65];
    const float* W = (bid < 8448) ? Wi : Wo;
    u16* Wt = (bid < 8448) ? wit : wot;
    int b2 = (bid < 8448) ? bid - 8192 : bid - 8448;
    int bx = b2 & 15, by = b2 >> 4;
    int tx = tid & 63, tw = tid >> 6;
    for (int r = tw; r < 64; r += 4)
      tile[r][tx] = W[(size_t)(by * 64 + r) * 1024 + bx * 64 + tx];
    __syncthreads();
    for (int r = tw; r < 64; r += 4)
      Wt[(size_t)(bx * 64 + r) * 1024 + by * 64 + tx] = f2bf(tile[tx][r]);
  } else if (bid < 14848) {
    const float* w = (bid < 11776) ? w1 : w2;
    u16* Wt = (bid < 11776) ? w1t : w2t;
    int vb = (bid < 11776) ? bid - 8704 : bid - 11776;
    int base = (vb * 256 + tid) * 4;                 // [0, 3145728)
    int o = base / 3072, rem = base % 3072;
    int dt = rem >> 10, i0 = rem & 1023;
    const float* src = w + (size_t)o * 3072 + dt;
    ushort4 v;
    v.x = f2bf(src[(i0 + 0) * 3]);
    v.y = f2bf(src[(i0 + 1) * 3]);
    v.z = f2bf(src[(i0 + 2) * 3]);
    v.w = f2bf(src[(i0 + 3) * 3]);
    *(ushort4*)(Wt + base) = v;
  } else {
    int idx = (bid - 14848) * 256 + tid;             // [0, 1048576)
    int tr = idx >> 9, j0 = (idx & 511) * 4;
    float b1v = be1[0], b2v = be2[0];
    ushort4 v;
#pragma unroll
    for (int q = 0; q < 4; q++) {
      int j = j0 + q;
      float vv = 0.f;
      if (tr >= j) vv += b1v * kf[tr - j];
      if (j >= tr) vv += b2v * kb[j - tr];
      ((u16*)&v)[q] = f2bf(vv);
    }
    *(ushort4*)(Tm + (size_t)tr * 2048 + j0) = v;
  }
}

__global__ __launch_bounds__(256) void trans_h(const u16* __restrict__ hpad, u16* __restrict__ ht) {
  __shared__ u16 tile[64][66];
  int b = blockIdx.z;
  int lt = blockIdx.x * 64, dt = blockIdx.y * 64;
  int tx = threadIdx.x & 15, ty = threadIdx.x >> 4;   // 16 x 16
  const u16* src = hpad + (size_t)b * LPq * Dq + (size_t)(lt + 1 + ty) * Dq + dt + tx * 4;
#pragma unroll
  for (int i = 0; i < 4; i++) {
    int r = ty + i * 16;
    ushort4 v = *(const ushort4*)(src + (size_t)i * 16 * Dq);
    tile[tx * 4 + 0][r] = v.x;
    tile[tx * 4 + 1][r] = v.y;
    tile[tx * 4 + 2][r] = v.z;
    tile[tx * 4 + 3][r] = v.w;
  }
  __syncthreads();
#pragma unroll
  for (int i = 0; i < 4; i++) {
    int d = ty + i * 16;
    ushort4 v;
    v.x = tile[d][tx * 4 + 0];
    v.y = tile[d][tx * 4 + 1];
    v.z = tile[d][tx * 4 + 2];
    v.w = tile[d][tx * 4 + 3];
    *(ushort4*)(ht + ((size_t)b * Dq + dt + d) * Lq + lt + tx * 4) = v;
  }
}

// ---------------- LayerNorm (wave per row) ----------------

__global__ __launch_bounds__(256) void ln1_k(const u16* __restrict__ h0, u16* __restrict__ hpad,
                                             const float* __restrict__ g, const float* __restrict__ be) {
  int w = threadIdx.x >> 6, lane = threadIdx.x & 63;
  int r = blockIdx.x * 4 + w;
  int d0 = lane * 16;
  const u16* hp = h0 + (size_t)r * 1024 + d0;
  bf16x8 va = *(const bf16x8*)hp;
  bf16x8 vb = *(const bf16x8*)(hp + 8);
  float v[16];
#pragma unroll
  for (int i = 0; i < 8; i++) { v[i] = bf2f((u16)va[i]); v[8 + i] = bf2f((u16)vb[i]); }
  float s = 0.f, q = 0.f;
#pragma unroll
  for (int i = 0; i < 16; i++) { s += v[i]; q += v[i] * v[i]; }
#pragma unroll
  for (int o = 32; o > 0; o >>= 1) { s += __shfl_xor(s, o); q += __shfl_xor(q, o); }
  float mean = s * (1.f / 1024.f);
  float rstd = rsqrtf(q * (1.f / 1024.f) - mean * mean + 1e-5f);
  const float4* g4 = (const float4*)(g + d0);
  const float4* b4 = (const float4*)(be + d0);
  u16 o16[16];
#pragma unroll
  for (int i = 0; i < 4; i++) {
    float4 gv = g4[i], bv = b4[i];
    o16[i * 4 + 0] = f2bf((v[i * 4 + 0] - mean) * rstd * gv.x + bv.x);
    o16[i * 4 + 1] = f2bf((v[i * 4 + 1] - mean) * rstd * gv.y + bv.y);
    o16[i * 4 + 2] = f2bf((v[i * 4 + 2] - mean) * rstd * gv.z + bv.z);
    o16[i * 4 + 3] = f2bf((v[i * 4 + 3] - mean) * rstd * gv.w + bv.w);
  }
  int b_ = r >> 11, l = r & 2047;
  u16* dst = hpad + ((size_t)b_ * LPq + l + 1) * Dq + d0;
  *(bf16x8*)dst = *(const bf16x8*)o16;
  *(bf16x8*)(dst + 8) = *(const bf16x8*)(o16 + 8);
}

__global__ __launch_bounds__(256) void ln2_k(const u16* __restrict__ hp, const float* __restrict__ x,
                                             const float* __restrict__ g, const float* __restrict__ be,
                                             float* __restrict__ out) {
  int w = threadIdx.x >> 6, lane = threadIdx.x & 63;
  size_t r = (size_t)blockIdx.x * 4 + w;
  int d0 = lane * 16;
  size_t base = r * 1024 + d0;
  const u16* h = hp + base;
  bf16x8 va = *(const bf16x8*)h;
  bf16x8 vb = *(const bf16x8*)(h + 8);
  float v[16];
#pragma unroll
  for (int i = 0; i < 8; i++) { v[i] = bf2f((u16)va[i]); v[8 + i] = bf2f((u16)vb[i]); }
  float s = 0.f, q = 0.f;
#pragma unroll
  for (int i = 0; i < 16; i++) { s += v[i]; q += v[i] * v[i]; }
#pragma unroll
  for (int o = 32; o > 0; o >>= 1) { s += __shfl_xor(s, o); q += __shfl_xor(q, o); }
  float mean = s * (1.f / 1024.f);
  float rstd = rsqrtf(q * (1.f / 1024.f) - mean * mean + 1e-5f);
  const float4* g4 = (const float4*)(g + d0);
  const float4* b4 = (const float4*)(be + d0);
  const float4* x4 = (const float4*)(x + base);
  float4* o4 = (float4*)(out + base);
#pragma unroll
  for (int i = 0; i < 4; i++) {
    float4 gv = g4[i], bv = b4[i], xv = x4[i];
    float4 o;
    o.x = xv.x + (v[i * 4 + 0] - mean) * rstd * gv.x + bv.x;
    o.y = xv.y + (v[i * 4 + 1] - mean) * rstd * gv.y + bv.y;
    o.z = xv.z + (v[i * 4 + 2] - mean) * rstd * gv.z + bv.z;
    o.w = xv.w + (v[i * 4 + 3] - mean) * rstd * gv.w + bv.w;
    o4[i] = o;
  }
}

// ---------------- 8-wave 256x256 pipelined MFMA core (ring-4, 32x32x16 MFMA) ----------------
// Staging/schedule identical to R10 (proven: 0 bank conflicts). Fragment reads switched to
// mfma_f32_32x32x16_bf16: A row=lane&31, k=(lane>>5)*8+i (contig-8); B mirrored.
// C/D (HW-verified m74/m101): col=lane&31, row=(reg&3)+8*(reg>>2)+4*(lane>>5).
// Per wave per 32-K subtile: 16 MFMA (vs 32) and 12 ds_read_b128 (vs 24).
// NOTE: 128 KB LDS -> 1 block/CU by design; do NOT raise waves/EU (R9: acc spills).
__device__ __forceinline__ void gemm_core(const u16* __restrict__ Ab, int lda,
                                          const u16* __restrict__ Bb, int ldb,
                                          int ks, int NS, u16* lds,
                                          f32x16 (&acc)[4][2]) {
  const int t = threadIdx.x;
  const int lane = t & 63, w = t >> 6;
  const int g = w >> 2, j = w & 3;
  // staging map: chunk q -> (row, fkc)  [identical to R10]
  const int p1 = t >> 3;
  const int c1 = (t & 7) ^ (p1 & 7);
  const int row1 = (p1 << 1) | (c1 >> 2), f1 = c1 & 3;
  const int q2 = t + 512;
  const int p2 = q2 >> 3;
  const int c2 = (q2 & 7) ^ (p2 & 7);
  const int row2 = (p2 << 1) | (c2 >> 2), f2 = c2 & 3;
  const int aoff1 = row1 * lda + f1 * 8;
  const int aoff2 = row2 * lda + f2 * 8;
  const int boff1 = row1 * ldb + f1 * 8;
  const int boff2 = row2 * ldb + f2 * 8;
  u16* wA1 = lds + t * 8;            // + slot*16384 (u16 units)
  u16* wA2 = lds + 4096 + t * 8;
  u16* wB1 = lds + 8192 + t * 8;
  u16* wB2 = lds + 12288 + t * 8;
  // read map (32x32 fragments)
  const int r32 = lane & 31, kh = lane >> 5;
  int aadr[4][2], badr[2][2];
#pragma unroll
  for (int mf = 0; mf < 4; mf++)
#pragma unroll
    for (int kk = 0; kk < 2; kk++) {
      int r = g * 128 + mf * 32 + r32;
      int p = r >> 1, c = ((r & 1) << 2) | (kk * 2 + kh);
      aadr[mf][kk] = p * 64 + ((c ^ (p & 7)) << 3);
    }
#pragma unroll
  for (int nf = 0; nf < 2; nf++)
#pragma unroll
    for (int kk = 0; kk < 2; kk++) {
      int r = j * 64 + nf * 32 + r32;
      int p = r >> 1, c = ((r & 1) << 2) | (kk * 2 + kh);
      badr[nf][kk] = 8192 + p * 64 + ((c ^ (p & 7)) << 3);
    }

#define STAGE_A(s_) { int sl_ = ((s_) & 3) * 16384; const u16* g_ = Ab + ks + (s_) * 32; \
    gld16(g_ + aoff1, wA1 + sl_); gld16(g_ + aoff2, wA2 + sl_); }
#define STAGE_B(s_) { int sl_ = ((s_) & 3) * 16384; const u16* g_ = Bb + ks + (s_) * 32; \
    gld16(g_ + boff1, wB1 + sl_); gld16(g_ + boff2, wB2 + sl_); }

  // prologue: stage subtiles 0..2
  STAGE_A(0); STAGE_B(0);
  STAGE_A(1); STAGE_B(1);
  STAGE_A(2); STAGE_B(2);

  for (int s = 0; s < NS; s++) {
    const u16* sl = lds + (s & 3) * 16384;
    if (s <= NS - 3)      { asm volatile("s_waitcnt vmcnt(8)" ::: "memory"); }
    else if (s == NS - 2) { asm volatile("s_waitcnt vmcnt(4)" ::: "memory"); }
    else                  { asm volatile("s_waitcnt vmcnt(0)" ::: "memory"); }
    asm volatile("s_barrier" ::: "memory");
    if (s + 3 < NS) STAGE_A(s + 3);
    bf16x8 b0[2], b1[2], a0[4], a1[4];
#pragma unroll
    for (int nf = 0; nf < 2; nf++) {
      b0[nf] = *(const bf16x8*)(sl + badr[nf][0]);
      b1[nf] = *(const bf16x8*)(sl + badr[nf][1]);
    }
#pragma unroll
    for (int mf = 0; mf < 4; mf++) a0[mf] = *(const bf16x8*)(sl + aadr[mf][0]);
    __builtin_amdgcn_s_setprio(1);
#pragma unroll
    for (int mf = 0; mf < 4; mf++)
#pragma unroll
      for (int nf = 0; nf < 2; nf++)
        acc[mf][nf] = __builtin_amdgcn_mfma_f32_32x32x16_bf16(a0[mf], b0[nf], acc[mf][nf], 0, 0, 0);
    __builtin_amdgcn_s_setprio(0);
    if (s + 3 < NS) STAGE_B(s + 3);
#pragma unroll
    for (int mf = 0; mf < 4; mf++) a1[mf] = *(const bf16x8*)(sl + aadr[mf][1]);
    __builtin_amdgcn_s_setprio(1);
#pragma unroll
    for (int mf = 0; mf < 4; mf++)
#pragma unroll
      for (int nf = 0; nf < 2; nf++)
        acc[mf][nf] = __builtin_amdgcn_mfma_f32_32x32x16_bf16(a1[mf], b1[nf], acc[mf][nf], 0, 0, 0);
    __builtin_amdgcn_s_setprio(0);
  }
#undef STAGE_A
#undef STAGE_B
}

// MODE 0: out = acc + bias ; MODE 1: silu(acc+bias) ; MODE 2: acc + bias + out_old (in-place)
template <int MODE>
__global__ __launch_bounds__(512, 2) void gemm8(
    const u16* __restrict__ A, int lda, long abstr,
    const u16* __restrict__ Bw, int ldb,
    u16* __restrict__ Out, long obstr,
    const float* __restrict__ bias, int K, int nbm) {
  __shared__ __align__(16) u16 lds[65536];
  int mb = blockIdx.x % nbm, nb = blockIdx.x / nbm;
  int m0 = mb * 256, n0 = nb * 256;
  int batch = m0 >> 11, r0 = m0 & 2047;
  const u16* Ab = A + (size_t)batch * abstr + (size_t)r0 * lda;
  const u16* Bb = Bw + (size_t)n0 * ldb;
  f32x16 acc[4][2] = {};
  gemm_core(Ab, lda, Bb, ldb, 0, K >> 5, lds, acc);
  int lane = threadIdx.x & 63, w = threadIdx.x >> 6;
  int g = w >> 2, j = w & 3;
  int r32 = lane & 31, kh = lane >> 5;
  u16* ob = Out + (size_t)batch * obstr;
#pragma unroll
  for (int mf = 0; mf < 4; mf++) {
#pragma unroll
    for (int nf = 0; nf < 2; nf++) {
      int col = n0 + j * 64 + nf * 32 + r32;
      float bv = bias[col];
      f32x16 a = acc[mf][nf];
#pragma unroll
      for (int q = 0; q < 4; q++) {
        int row = r0 + g * 128 + mf * 32 + q * 8 + 4 * kh;
        u16* op = ob + (size_t)row * 1024 + col;
#pragma unroll
        for (int i = 0; i < 4; i++) {
          float v = a[q * 4 + i] + bv;
          if (MODE == 1) v = v / (1.f + __expf(-v));
          if (MODE == 2) v += bf2f(op[(size_t)i * 1024]);
          op[(size_t)i * 1024] = f2bf(v);
        }
      }
    }
  }
}

// Fused conv1 + dense SSM (independent after ln1/trans_h), 512 blocks.
// [0,256): conv1 (silu): M=16384 (64 mb), N=1024 (4 nb), K=3072
// [256,512): ssm: hmix[t,(b,d)] = ns[b,d] * (T @ H)[t,(b,d)]; M=2048 (8 mb), N=8192 (32 nb), K=2048
__global__ __launch_bounds__(512, 2) void mix8(
    const u16* __restrict__ hpad, const u16* __restrict__ w1t,
    u16* __restrict__ co, const float* __restrict__ bc1,
    const u16* __restrict__ Tm, const u16* __restrict__ Ht,
    const float* __restrict__ ns, u16* __restrict__ hmix) {
  __shared__ __align__(16) u16 lds[65536];
  const long PSTR = (long)LPq * 1024;
  int id = blockIdx.x;
  int lane = threadIdx.x & 63, w = threadIdx.x >> 6;
  int g = w >> 2, j = w & 3;
  int r32 = lane & 31, kh = lane >> 5;
  if (id < 256) {
    int mb = id & 63, nb = id >> 6;
    int m0 = mb * 256, n0 = nb * 256;
    int batch = m0 >> 11, r0 = m0 & 2047;
    const u16* Ab = hpad + (size_t)batch * PSTR + (size_t)r0 * 1024;
    const u16* Bb = w1t + (size_t)n0 * 3072;
    f32x16 acc[4][2] = {};
    gemm_core(Ab, 1024, Bb, 3072, 0, 96, lds, acc);
    u16* ob = co + (size_t)batch * PSTR;
#pragma unroll
    for (int mf = 0; mf < 4; mf++) {
#pragma unroll
      for (int nf = 0; nf < 2; nf++) {
        int col = n0 + j * 64 + nf * 32 + r32;
        float bv = bc1[col];
        f32x16 a = acc[mf][nf];
#pragma unroll
        for (int q = 0; q < 4; q++) {
          int row = r0 + g * 128 + mf * 32 + q * 8 + 4 * kh;
          u16* op = ob + (size_t)row * 1024 + col;
#pragma unroll
          for (int i = 0; i < 4; i++) {
            float v = a[q * 4 + i] + bv;
            v = v / (1.f + __expf(-v));
            op[(size_t)i * 1024] = f2bf(v);
          }
        }
      }
    }
  } else {
    int r = id - 256;
    int mb = r & 7, nb = r >> 3;
    int m0 = mb * 256, n0 = nb * 256;
    const u16* Ab = Tm + (size_t)m0 * 2048;
    const u16* Bb = Ht + (size_t)n0 * 2048;
    f32x16 acc[4][2] = {};
    gemm_core(Ab, 2048, Bb, 2048, 0, 64, lds, acc);
#pragma unroll
    for (int mf = 0; mf < 4; mf++) {
#pragma unroll
      for (int nf = 0; nf < 2; nf++) {
        int col = n0 + j * 64 + nf * 32 + r32;   // [0, 8192)
        int b = col >> 10, d = col & 1023;
        float cv = ns[col];
        f32x16 a = acc[mf][nf];
#pragma unroll
        for (int q = 0; q < 4; q++) {
          int row = m0 + g * 128 + mf * 32 + q * 8 + 4 * kh;
          u16* op = hmix + ((size_t)b * Lq + row) * 1024 + d;
#pragma unroll
          for (int i = 0; i < 4; i++)
            op[(size_t)i * 1024] = f2bf(a[q * 4 + i] * cv);
        }
      }
    }
  }
}

// ---------------- launch ----------------

extern "C" void kernel_launch(void* const* d_in, const int* in_sizes, int n_in,
                              void* d_out, int out_size, void* d_ws, size_t ws_size,
                              hipStream_t stream) {
  const float* x   = (const float*)d_in[0];
  const float* tt  = (const float*)d_in[1];
  const float* be1 = (const float*)d_in[2];
  const float* be2 = (const float*)d_in[3];
  const float* Wi  = (const float*)d_in[4];
  const float* bi  = (const float*)d_in[5];
  const float* Wo  = (const float*)d_in[6];
  const float* bo  = (const float*)d_in[7];
  const float* w1  = (const float*)d_in[8];
  const float* bc1 = (const float*)d_in[9];
  const float* w2  = (const float*)d_in[10];
  const float* bc2 = (const float*)d_in[11];
  const float* g1  = (const float*)d_in[12];
  const float* b1  = (const float*)d_in[13];
  const float* g2  = (const float*)d_in[14];
  const float* b2  = (const float*)d_in[15];
  const float* Af  = (const float*)d_in[16];
  const float* Bf  = (const float*)d_in[17];
  const float* Cf  = (const float*)d_in[18];
  const float* Df  = (const float*)d_in[19];
  const float* Ab  = (const float*)d_in[20];
  const float* Bb  = (const float*)d_in[21];
  const float* Cb  = (const float*)d_in[22];
  const float* Db  = (const float*)d_in[23];

  char* p = (char*)d_ws;
  constexpr size_t SZ_h0   = (size_t)16384 * 1024 * 2;
  constexpr size_t SZ_hpad = (size_t)Bq * LPq * Dq * 2;
  constexpr size_t SZ_ht   = (size_t)Bq * Dq * Lq * 2;
  constexpr size_t SZ_hmix = (size_t)16384 * 1024 * 2;
  constexpr size_t SZ_T    = (size_t)2048 * 2048 * 2;
  constexpr size_t SZ_wt   = (size_t)1024 * 1024 * 2;
  constexpr size_t SZ_w3t  = (size_t)1024 * 3072 * 2;

  size_t off = 0;
  u16* h0    = (u16*)(p + off); off += SZ_h0;      // later reused for Wo output
  u16* hpad  = (u16*)(p + off); off += SZ_hpad;
  u16* ht    = (u16*)(p + off); off += SZ_ht;
  u16* copad = (u16*)(p + off); off += SZ_hpad;
  u16* hmixF = (u16*)(p + off); off += SZ_hmix;    // overlaid with xb (xb dead after Wi GEMM)
  u16* Tmat  = (u16*)(p + off); off += SZ_T;
  u16* wit   = (u16*)(p + off); off += SZ_wt;
  u16* wot   = (u16*)(p + off); off += SZ_wt;
  u16* w1t   = (u16*)(p + off); off += SZ_w3t;
  u16* w2t   = (u16*)(p + off); off += SZ_w3t;
  float* kf  = (float*)(p + off); off += 8192;
  float* kb  = (float*)(p + off); off += 8192;
  float* nsb = (float*)(p + off); off += 32768;
  u16* xb    = hmixF;  // overlay

  const long BSTR = (long)2048 * 1024;
  const long PSTR = (long)LPq * 1024;

  // prep (2 dispatches: kf/kb must precede T-fill)
  prep_small<<<dim3(168), dim3(256), 0, stream>>>(tt, Af, Bf, Cf, Df,
                                                  Ab, Bb, Cb, Db, kf, kb, nsb, hpad, copad);
  mega_prep<<<dim3(18944), dim3(256), 0, stream>>>(x, xb, Wi, wit, Wo, wot,
                                                   w1, w1t, w2, w2t, kf, kb, be1, be2, Tmat);

  // h0 = x @ Wi + bi (bf16)
  gemm8<0><<<dim3(256), dim3(512), 0, stream>>>(xb, 1024, BSTR, wit, 1024, h0, BSTR, bi, 1024, 64);
  // LN1 -> hpad
  ln1_k<<<dim3(4096), dim3(256), 0, stream>>>(h0, hpad, g1, b1);
  // Ht = transpose(h)
  trans_h<<<dim3(32, 16, 8), dim3(256), 0, stream>>>(hpad, ht);
  // fused: conv1+silu -> copad rows 1..L ; ssm -> hmixF = ns * (T @ H)
  mix8<<<dim3(512), dim3(512), 0, stream>>>(hpad, w1t, copad + 1024, bc1,
                                            Tmat, ht, nsb, hmixF);
  // conv2: hmixF += acc + bc2 (in-place)
  gemm8<2><<<dim3(256), dim3(512), 0, stream>>>(copad, 1024, PSTR, w2t, 3072, hmixF, BSTR, bc2, 3072, 64);
  // out_pre = hmixF @ Wo + bo -> h0
  gemm8<0><<<dim3(256), dim3(512), 0, stream>>>(hmixF, 1024, BSTR, wot, 1024, h0, BSTR, bo, 1024, 64);
  // out = x + LN2(out_pre)
  ln2_k<<<dim3(4096), dim3(256), 0, stream>>>(h0, x, g2, b2, (float*)d_out);
}

// Round 12
// 407.259 us; speedup vs baseline: 1.1738x; 1.1738x over previous
//
#include <hip/hip_runtime.h>

// DiffSSM: B=8, L=2048, D=1024, N=64
#define Bq 8
#define Lq 2048
#define Dq 1024
#define LPq 2050  // L + 2 pad rows

typedef unsigned short u16;
typedef __attribute__((ext_vector_type(8))) short bf16x8;
typedef __attribute__((ext_vector_type(4))) float f32x4;

__device__ __forceinline__ u16 f2bf(float f) {
  unsigned u = __float_as_uint(f);
  u += 0x7FFFu + ((u >> 16) & 1u);   // RNE
  return (u16)(u >> 16);
}
__device__ __forceinline__ float bf2f(u16 s) {
  return __uint_as_float(((unsigned)s) << 16);
}
__device__ __forceinline__ void gld16(const u16* g, u16* l) {
  __builtin_amdgcn_global_load_lds((const __attribute__((address_space(1))) void*)g,
                                   (__attribute__((address_space(3))) void*)l, 16, 0, 0);
}

// ---------------- prep ----------------

// blocks 0-7: kf/kb (2048); blocks 8-39: ns (8192); blocks 40-167: zero pads
__global__ __launch_bounds__(256) void prep_small(
    const float* __restrict__ t,
    const float* __restrict__ Af, const float* __restrict__ Bf, const float* __restrict__ Cf, const float* __restrict__ Df,
    const float* __restrict__ Ab, const float* __restrict__ Bb, const float* __restrict__ Cb, const float* __restrict__ Db,
    float* __restrict__ kf, float* __restrict__ kb,
    float* __restrict__ ns,
    u16* __restrict__ hpad, u16* __restrict__ copad) {
  int tid = blockIdx.x * 256 + threadIdx.x;
  if (blockIdx.x < 8) {
    int l = tid;
    float sf = Df[0], sb = Db[0];
    for (int n = 0; n < 64; n++) {
      sf += __expf((float)l * Af[n * 64 + n]) * (Bf[n] * Cf[n]);
      sb += __expf((float)l * Ab[n * 64 + n]) * (Bb[n] * Cb[n]);
    }
    kf[l] = sf; kb[l] = sb;
  } else if (blockIdx.x < 40) {
    int i = tid - 2048;                 // [0, 8192)
    int b = i >> 10, d = i & 1023;
    float tb = t[b];
    float e;
    if (d < 512) {
      float f = __expf((float)d * (-logf(10000.f) / 511.f));
      e = sinf(tb * f);
    } else {
      float f = __expf((float)(d - 512) * (-logf(10000.f) / 511.f));
      e = cosf(tb * f);
    }
    ns[i] = 1.f / (1.f + __expf(-e));
  } else {
    int i = tid - 10240;                // [0, 32768)
    if (i < 32768) {
      int d = i & 1023;
      int j = i >> 10;                  // [0,32)
      int arr = j & 1, r = (j >> 1) & 1, b = j >> 2;
      size_t off = (size_t)b * LPq * Dq + (r ? (size_t)(LPq - 1) * Dq : 0) + d;
      if (arr == 0) hpad[off] = 0;
      else          copad[off] = 0;
    }
  }
}

// mega prep: [0,8192) cast_x | [8192,8448) trans_w Wi | [8448,8704) trans_w Wo |
// [8704,11776) trans_w3 w1 | [11776,14848) trans_w3 w2 |
// [14848,18944) T-fill: T[t][j] = b1*(t>=j?kf[t-j]:0) + b2*(j>=t?kb[j-t]:0)
__global__ __launch_bounds__(256) void mega_prep(
    const float* __restrict__ x, u16* __restrict__ xb,
    const float* __restrict__ Wi, u16* __restrict__ wit,
    const float* __restrict__ Wo, u16* __restrict__ wot,
    const float* __restrict__ w1, u16* __restrict__ w1t,
    const float* __restrict__ w2, u16* __restrict__ w2t,
    const float* __restrict__ kf, const float* __restrict__ kb,
    const float* __restrict__ be1, const float* __restrict__ be2,
    u16* __restrict__ Tm) {
  int bid = blockIdx.x, tid = threadIdx.x;
  if (bid < 8192) {
    size_t i = ((size_t)bid * 256 + tid) * 8;
    float4 a = *(const float4*)(x + i);
    float4 b = *(const float4*)(x + i + 4);
    u16 o[8] = {f2bf(a.x), f2bf(a.y), f2bf(a.z), f2bf(a.w),
                f2bf(b.x), f2bf(b.y), f2bf(b.z), f2bf(b.w)};
    *(bf16x8*)(xb + i) = *(const bf16x8*)o;
  } else if (bid < 8704) {
    __shared__ float tile[64][65];
    const float* W = (bid < 8448) ? Wi : Wo;
    u16* Wt = (bid < 8448) ? wit : wot;
    int b2 = (bid < 8448) ? bid - 8192 : bid - 8448;
    int bx = b2 & 15, by = b2 >> 4;
    int tx = tid & 63, tw = tid >> 6;
    for (int r = tw; r < 64; r += 4)
      tile[r][tx] = W[(size_t)(by * 64 + r) * 1024 + bx * 64 + tx];
    __syncthreads();
    for (int r = tw; r < 64; r += 4)
      Wt[(size_t)(bx * 64 + r) * 1024 + by * 64 + tx] = f2bf(tile[tx][r]);
  } else if (bid < 14848) {
    const float* w = (bid < 11776) ? w1 : w2;
    u16* Wt = (bid < 11776) ? w1t : w2t;
    int vb = (bid < 11776) ? bid - 8704 : bid - 11776;
    int base = (vb * 256 + tid) * 4;                 // [0, 3145728)
    int o = base / 3072, rem = base % 3072;
    int dt = rem >> 10, i0 = rem & 1023;
    const float* src = w + (size_t)o * 3072 + dt;
    ushort4 v;
    v.x = f2bf(src[(i0 + 0) * 3]);
    v.y = f2bf(src[(i0 + 1) * 3]);
    v.z = f2bf(src[(i0 + 2) * 3]);
    v.w = f2bf(src[(i0 + 3) * 3]);
    *(ushort4*)(Wt + base) = v;
  } else {
    int idx = (bid - 14848) * 256 + tid;             // [0, 1048576)
    int tr = idx >> 9, j0 = (idx & 511) * 4;
    float b1v = be1[0], b2v = be2[0];
    ushort4 v;
#pragma unroll
    for (int q = 0; q < 4; q++) {
      int j = j0 + q;
      float vv = 0.f;
      if (tr >= j) vv += b1v * kf[tr - j];
      if (j >= tr) vv += b2v * kb[j - tr];
      ((u16*)&v)[q] = f2bf(vv);
    }
    *(ushort4*)(Tm + (size_t)tr * 2048 + j0) = v;
  }
}

__global__ __launch_bounds__(256) void trans_h(const u16* __restrict__ hpad, u16* __restrict__ ht) {
  __shared__ u16 tile[64][66];
  int b = blockIdx.z;
  int lt = blockIdx.x * 64, dt = blockIdx.y * 64;
  int tx = threadIdx.x & 15, ty = threadIdx.x >> 4;   // 16 x 16
  const u16* src = hpad + (size_t)b * LPq * Dq + (size_t)(lt + 1 + ty) * Dq + dt + tx * 4;
#pragma unroll
  for (int i = 0; i < 4; i++) {
    int r = ty + i * 16;
    ushort4 v = *(const ushort4*)(src + (size_t)i * 16 * Dq);
    tile[tx * 4 + 0][r] = v.x;
    tile[tx * 4 + 1][r] = v.y;
    tile[tx * 4 + 2][r] = v.z;
    tile[tx * 4 + 3][r] = v.w;
  }
  __syncthreads();
#pragma unroll
  for (int i = 0; i < 4; i++) {
    int d = ty + i * 16;
    ushort4 v;
    v.x = tile[d][tx * 4 + 0];
    v.y = tile[d][tx * 4 + 1];
    v.z = tile[d][tx * 4 + 2];
    v.w = tile[d][tx * 4 + 3];
    *(ushort4*)(ht + ((size_t)b * Dq + dt + d) * Lq + lt + tx * 4) = v;
  }
}

// ---------------- LayerNorm (wave per row) ----------------

__global__ __launch_bounds__(256) void ln1_k(const u16* __restrict__ h0, u16* __restrict__ hpad,
                                             const float* __restrict__ g, const float* __restrict__ be) {
  int w = threadIdx.x >> 6, lane = threadIdx.x & 63;
  int r = blockIdx.x * 4 + w;
  int d0 = lane * 16;
  const u16* hp = h0 + (size_t)r * 1024 + d0;
  bf16x8 va = *(const bf16x8*)hp;
  bf16x8 vb = *(const bf16x8*)(hp + 8);
  float v[16];
#pragma unroll
  for (int i = 0; i < 8; i++) { v[i] = bf2f((u16)va[i]); v[8 + i] = bf2f((u16)vb[i]); }
  float s = 0.f, q = 0.f;
#pragma unroll
  for (int i = 0; i < 16; i++) { s += v[i]; q += v[i] * v[i]; }
#pragma unroll
  for (int o = 32; o > 0; o >>= 1) { s += __shfl_xor(s, o); q += __shfl_xor(q, o); }
  float mean = s * (1.f / 1024.f);
  float rstd = rsqrtf(q * (1.f / 1024.f) - mean * mean + 1e-5f);
  const float4* g4 = (const float4*)(g + d0);
  const float4* b4 = (const float4*)(be + d0);
  u16 o16[16];
#pragma unroll
  for (int i = 0; i < 4; i++) {
    float4 gv = g4[i], bv = b4[i];
    o16[i * 4 + 0] = f2bf((v[i * 4 + 0] - mean) * rstd * gv.x + bv.x);
    o16[i * 4 + 1] = f2bf((v[i * 4 + 1] - mean) * rstd * gv.y + bv.y);
    o16[i * 4 + 2] = f2bf((v[i * 4 + 2] - mean) * rstd * gv.z + bv.z);
    o16[i * 4 + 3] = f2bf((v[i * 4 + 3] - mean) * rstd * gv.w + bv.w);
  }
  int b_ = r >> 11, l = r & 2047;
  u16* dst = hpad + ((size_t)b_ * LPq + l + 1) * Dq + d0;
  *(bf16x8*)dst = *(const bf16x8*)o16;
  *(bf16x8*)(dst + 8) = *(const bf16x8*)(o16 + 8);
}

__global__ __launch_bounds__(256) void ln2_k(const u16* __restrict__ hp, const float* __restrict__ x,
                                             const float* __restrict__ g, const float* __restrict__ be,
                                             float* __restrict__ out) {
  int w = threadIdx.x >> 6, lane = threadIdx.x & 63;
  size_t r = (size_t)blockIdx.x * 4 + w;
  int d0 = lane * 16;
  size_t base = r * 1024 + d0;
  const u16* h = hp + base;
  bf16x8 va = *(const bf16x8*)h;
  bf16x8 vb = *(const bf16x8*)(h + 8);
  float v[16];
#pragma unroll
  for (int i = 0; i < 8; i++) { v[i] = bf2f((u16)va[i]); v[8 + i] = bf2f((u16)vb[i]); }
  float s = 0.f, q = 0.f;
#pragma unroll
  for (int i = 0; i < 16; i++) { s += v[i]; q += v[i] * v[i]; }
#pragma unroll
  for (int o = 32; o > 0; o >>= 1) { s += __shfl_xor(s, o); q += __shfl_xor(q, o); }
  float mean = s * (1.f / 1024.f);
  float rstd = rsqrtf(q * (1.f / 1024.f) - mean * mean + 1e-5f);
  const float4* g4 = (const float4*)(g + d0);
  const float4* b4 = (const float4*)(be + d0);
  const float4* x4 = (const float4*)(x + base);
  float4* o4 = (float4*)(out + base);
#pragma unroll
  for (int i = 0; i < 4; i++) {
    float4 gv = g4[i], bv = b4[i], xv = x4[i];
    float4 o;
    o.x = xv.x + (v[i * 4 + 0] - mean) * rstd * gv.x + bv.x;
    o.y = xv.y + (v[i * 4 + 1] - mean) * rstd * gv.y + bv.y;
    o.z = xv.z + (v[i * 4 + 2] - mean) * rstd * gv.z + bv.z;
    o.w = xv.w + (v[i * 4 + 3] - mean) * rstd * gv.w + bv.w;
    o4[i] = o;
  }
}

// ---------------- 8-wave 256x256 MFMA core: BK=64, ring-2 (2 x 64KB slots) ----------------
// 16x16x32 MFMA (R10-proven fragments/epilogue). LDS per slot: A[256][64] + B[256][64],
// XOR-swizzled per row (1 row = 128B = one full bank sweep): slot' = slot ^ (row&7).
// Reads keep the R10-proven 16-rows x 4-slots pattern (conflict-free class); kk=1
// fragment addresses = kk=0 addresses XOR 32 (u16 units).
// Ring-2 write-after-read safety: slot (s+1)&1 was last read during subtile s-1; all
// waves passed barrier(s) before any stage of s+1 is issued (R9-proven logic).
// vmcnt(0) at top of s waits loads issued one full subtile (~2600cy) earlier -> ~free.
// NOTE: 128 KB LDS -> 1 block/CU by design; do NOT raise waves/EU (R9: acc spills).
__device__ __forceinline__ void gemm_core(const u16* __restrict__ Ab, int lda,
                                          const u16* __restrict__ Bb, int ldb,
                                          int NS, u16* lds,
                                          f32x4 (&acc)[8][4]) {
  const int t = threadIdx.x;
  const int lane = t & 63, w = t >> 6;
  const int g = w >> 2, j = w & 3;
  // staging map: thread t stages chunks {t, t+512, t+1024, t+1536} of each 2048-chunk tile
  int aoff[4], boff[4];
#pragma unroll
  for (int q = 0; q < 4; q++) {
    int c = t + q * 512;
    int row = c >> 3;
    int slot = (c & 7) ^ (row & 7);
    aoff[q] = row * lda + slot * 8;
    boff[q] = row * ldb + slot * 8;
  }
  // read map (kk=0): A row = g*128 + mf*16 + frow, slot = lane>>4
  const int frow = lane & 15, f = lane >> 4;
  int aadr[8], badr[4];
#pragma unroll
  for (int mf = 0; mf < 8; mf++) {
    int row = g * 128 + mf * 16 + frow;
    aadr[mf] = row * 64 + ((f ^ (row & 7)) << 3);
  }
#pragma unroll
  for (int nf = 0; nf < 4; nf++) {
    int row = j * 64 + nf * 16 + frow;
    badr[nf] = 16384 + row * 64 + ((f ^ (row & 7)) << 3);
  }

#define STAGE_A(s_) { const u16* g_ = Ab + (s_) * 64; u16* l_ = lds + ((s_) & 1) * 32768; \
    gld16(g_ + aoff[0], l_ + t * 8);            gld16(g_ + aoff[1], l_ + (t + 512) * 8); \
    gld16(g_ + aoff[2], l_ + (t + 1024) * 8);   gld16(g_ + aoff[3], l_ + (t + 1536) * 8); }
#define STAGE_B(s_) { const u16* g_ = Bb + (s_) * 64; u16* l_ = lds + ((s_) & 1) * 32768 + 16384; \
    gld16(g_ + boff[0], l_ + t * 8);            gld16(g_ + boff[1], l_ + (t + 512) * 8); \
    gld16(g_ + boff[2], l_ + (t + 1024) * 8);   gld16(g_ + boff[3], l_ + (t + 1536) * 8); }

  STAGE_A(0); STAGE_B(0);

  for (int s = 0; s < NS; s++) {
    const u16* sl = lds + (s & 1) * 32768;
    asm volatile("s_waitcnt vmcnt(0)" ::: "memory");
    asm volatile("s_barrier" ::: "memory");
    if (s + 1 < NS) STAGE_A(s + 1);
    bf16x8 bq[4], af[4];
    // ---- kk = 0 ----
#pragma unroll
    for (int nf = 0; nf < 4; nf++) bq[nf] = *(const bf16x8*)(sl + badr[nf]);
#pragma unroll
    for (int mf = 0; mf < 4; mf++) af[mf] = *(const bf16x8*)(sl + aadr[mf]);
    __builtin_amdgcn_s_setprio(1);
#pragma unroll
    for (int mf = 0; mf < 4; mf++)
#pragma unroll
      for (int nf = 0; nf < 4; nf++)
        acc[mf][nf] = __builtin_amdgcn_mfma_f32_16x16x32_bf16(af[mf], bq[nf], acc[mf][nf], 0, 0, 0);
    __builtin_amdgcn_s_setprio(0);
    if (s + 1 < NS) STAGE_B(s + 1);
#pragma unroll
    for (int mf = 0; mf < 4; mf++) af[mf] = *(const bf16x8*)(sl + aadr[4 + mf]);
    __builtin_amdgcn_s_setprio(1);
#pragma unroll
    for (int mf = 0; mf < 4; mf++)
#pragma unroll
      for (int nf = 0; nf < 4; nf++)
        acc[4 + mf][nf] = __builtin_amdgcn_mfma_f32_16x16x32_bf16(af[mf], bq[nf], acc[4 + mf][nf], 0, 0, 0);
    __builtin_amdgcn_s_setprio(0);
    // ---- kk = 1 (addresses XOR 32) ----
#pragma unroll
    for (int nf = 0; nf < 4; nf++) bq[nf] = *(const bf16x8*)(sl + (badr[nf] ^ 32));
#pragma unroll
    for (int mf = 0; mf < 4; mf++) af[mf] = *(const bf16x8*)(sl + (aadr[mf] ^ 32));
    __builtin_amdgcn_s_setprio(1);
#pragma unroll
    for (int mf = 0; mf < 4; mf++)
#pragma unroll
      for (int nf = 0; nf < 4; nf++)
        acc[mf][nf] = __builtin_amdgcn_mfma_f32_16x16x32_bf16(af[mf], bq[nf], acc[mf][nf], 0, 0, 0);
    __builtin_amdgcn_s_setprio(0);
#pragma unroll
    for (int mf = 0; mf < 4; mf++) af[mf] = *(const bf16x8*)(sl + (aadr[4 + mf] ^ 32));
    __builtin_amdgcn_s_setprio(1);
#pragma unroll
    for (int mf = 0; mf < 4; mf++)
#pragma unroll
      for (int nf = 0; nf < 4; nf++)
        acc[4 + mf][nf] = __builtin_amdgcn_mfma_f32_16x16x32_bf16(af[mf], bq[nf], acc[4 + mf][nf], 0, 0, 0);
    __builtin_amdgcn_s_setprio(0);
  }
#undef STAGE_A
#undef STAGE_B
}

// MODE 0: out = acc + bias ; MODE 1: silu(acc+bias) ; MODE 2: acc + bias + out_old (in-place)
template <int MODE>
__global__ __launch_bounds__(512, 2) void gemm8(
    const u16* __restrict__ A, int lda, long abstr,
    const u16* __restrict__ Bw, int ldb,
    u16* __restrict__ Out, long obstr,
    const float* __restrict__ bias, int K, int nbm) {
  __shared__ __align__(16) u16 lds[65536];
  int mb = blockIdx.x % nbm, nb = blockIdx.x / nbm;
  int m0 = mb * 256, n0 = nb * 256;
  int batch = m0 >> 11, r0 = m0 & 2047;
  const u16* Ab = A + (size_t)batch * abstr + (size_t)r0 * lda;
  const u16* Bb = Bw + (size_t)n0 * ldb;
  f32x4 acc[8][4] = {};
  gemm_core(Ab, lda, Bb, ldb, K >> 6, lds, acc);
  int lane = threadIdx.x & 63, w = threadIdx.x >> 6;
  int g = w >> 2, j = w & 3;
  int frow = lane & 15;
  u16* ob = Out + (size_t)batch * obstr;
#pragma unroll
  for (int mf = 0; mf < 8; mf++) {
    int row = r0 + g * 128 + mf * 16 + ((lane >> 4) << 2);
#pragma unroll
    for (int nf = 0; nf < 4; nf++) {
      int col = n0 + j * 64 + nf * 16 + frow;
      float bv = bias[col];
      size_t base = (size_t)row * 1024 + col;
      f32x4 a = acc[mf][nf];
#pragma unroll
      for (int i = 0; i < 4; i++) {
        float v = a[i] + bv;
        if (MODE == 1) v = v / (1.f + __expf(-v));
        if (MODE == 2) v += bf2f(ob[base + (size_t)i * 1024]);
        ob[base + (size_t)i * 1024] = f2bf(v);
      }
    }
  }
}

// Fused conv1 + dense SSM (both depend only on ln1/trans_h), 512 blocks.
// [0,256): conv1 (silu): M=16384 (64 mb), N=1024 (4 nb), K=3072 (NS=48)
// [256,512): ssm: hmix = ns * (T @ H); M=2048 (8 mb), N=8192 (32 nb), K=2048 (NS=32)
// Blocks k and k+256 land on the same CU (round-robin) -> each CU runs one of each.
__global__ __launch_bounds__(512, 2) void mix8(
    const u16* __restrict__ hpad, const u16* __restrict__ w1t,
    u16* __restrict__ co, const float* __restrict__ bc1,
    const u16* __restrict__ Tm, const u16* __restrict__ Ht,
    const float* __restrict__ ns, u16* __restrict__ hmix) {
  __shared__ __align__(16) u16 lds[65536];
  const long PSTR = (long)LPq * 1024;
  int id = blockIdx.x;
  int lane = threadIdx.x & 63, w = threadIdx.x >> 6;
  int g = w >> 2, j = w & 3;
  int frow = lane & 15;
  if (id < 256) {
    int mb = id & 63, nb = id >> 6;
    int m0 = mb * 256, n0 = nb * 256;
    int batch = m0 >> 11, r0 = m0 & 2047;
    const u16* Ab = hpad + (size_t)batch * PSTR + (size_t)r0 * 1024;
    const u16* Bb = w1t + (size_t)n0 * 3072;
    f32x4 acc[8][4] = {};
    gemm_core(Ab, 1024, Bb, 3072, 48, lds, acc);
    u16* ob = co + (size_t)batch * PSTR;
#pragma unroll
    for (int mf = 0; mf < 8; mf++) {
      int row = r0 + g * 128 + mf * 16 + ((lane >> 4) << 2);
#pragma unroll
      for (int nf = 0; nf < 4; nf++) {
        int col = n0 + j * 64 + nf * 16 + frow;
        float bv = bc1[col];
        size_t base = (size_t)row * 1024 + col;
        f32x4 a = acc[mf][nf];
#pragma unroll
        for (int i = 0; i < 4; i++) {
          float v = a[i] + bv;
          v = v / (1.f + __expf(-v));
          ob[base + (size_t)i * 1024] = f2bf(v);
        }
      }
    }
  } else {
    int r = id - 256;
    int mb = r & 7, nb = r >> 3;
    int m0 = mb * 256, n0 = nb * 256;
    const u16* Ab = Tm + (size_t)m0 * 2048;
    const u16* Bb = Ht + (size_t)n0 * 2048;
    f32x4 acc[8][4] = {};
    gemm_core(Ab, 2048, Bb, 2048, 32, lds, acc);
#pragma unroll
    for (int mf = 0; mf < 8; mf++) {
      int row = m0 + g * 128 + mf * 16 + ((lane >> 4) << 2);
#pragma unroll
      for (int nf = 0; nf < 4; nf++) {
        int col = n0 + j * 64 + nf * 16 + frow;   // [0, 8192)
        int b = col >> 10, d = col & 1023;
        float cv = ns[col];
        u16* op = hmix + ((size_t)b * Lq + row) * 1024 + d;
        f32x4 a = acc[mf][nf];
#pragma unroll
        for (int i = 0; i < 4; i++)
          op[(size_t)i * 1024] = f2bf(a[i] * cv);
      }
    }
  }
}

// ---------------- launch ----------------

extern "C" void kernel_launch(void* const* d_in, const int* in_sizes, int n_in,
                              void* d_out, int out_size, void* d_ws, size_t ws_size,
                              hipStream_t stream) {
  const float* x   = (const float*)d_in[0];
  const float* tt  = (const float*)d_in[1];
  const float* be1 = (const float*)d_in[2];
  const float* be2 = (const float*)d_in[3];
  const float* Wi  = (const float*)d_in[4];
  const float* bi  = (const float*)d_in[5];
  const float* Wo  = (const float*)d_in[6];
  const float* bo  = (const float*)d_in[7];
  const float* w1  = (const float*)d_in[8];
  const float* bc1 = (const float*)d_in[9];
  const float* w2  = (const float*)d_in[10];
  const float* bc2 = (const float*)d_in[11];
  const float* g1  = (const float*)d_in[12];
  const float* b1  = (const float*)d_in[13];
  const float* g2  = (const float*)d_in[14];
  const float* b2  = (const float*)d_in[15];
  const float* Af  = (const float*)d_in[16];
  const float* Bf  = (const float*)d_in[17];
  const float* Cf  = (const float*)d_in[18];
  const float* Df  = (const float*)d_in[19];
  const float* Ab  = (const float*)d_in[20];
  const float* Bb  = (const float*)d_in[21];
  const float* Cb  = (const float*)d_in[22];
  const float* Db  = (const float*)d_in[23];

  char* p = (char*)d_ws;
  constexpr size_t SZ_h0   = (size_t)16384 * 1024 * 2;
  constexpr size_t SZ_hpad = (size_t)Bq * LPq * Dq * 2;
  constexpr size_t SZ_ht   = (size_t)Bq * Dq * Lq * 2;
  constexpr size_t SZ_hmix = (size_t)16384 * 1024 * 2;
  constexpr size_t SZ_T    = (size_t)2048 * 2048 * 2;
  constexpr size_t SZ_wt   = (size_t)1024 * 1024 * 2;
  constexpr size_t SZ_w3t  = (size_t)1024 * 3072 * 2;

  size_t off = 0;
  u16* h0    = (u16*)(p + off); off += SZ_h0;      // later reused for Wo output
  u16* hpad  = (u16*)(p + off); off += SZ_hpad;
  u16* ht    = (u16*)(p + off); off += SZ_ht;
  u16* copad = (u16*)(p + off); off += SZ_hpad;
  u16* hmixF = (u16*)(p + off); off += SZ_hmix;    // overlaid with xb (xb dead after Wi GEMM)
  u16* Tmat  = (u16*)(p + off); off += SZ_T;
  u16* wit   = (u16*)(p + off); off += SZ_wt;
  u16* wot   = (u16*)(p + off); off += SZ_wt;
  u16* w1t   = (u16*)(p + off); off += SZ_w3t;
  u16* w2t   = (u16*)(p + off); off += SZ_w3t;
  float* kf  = (float*)(p + off); off += 8192;
  float* kb  = (float*)(p + off); off += 8192;
  float* nsb = (float*)(p + off); off += 32768;
  u16* xb    = hmixF;  // overlay

  const long BSTR = (long)2048 * 1024;
  const long PSTR = (long)LPq * 1024;

  // prep (2 dispatches: kf/kb must precede T-fill)
  prep_small<<<dim3(168), dim3(256), 0, stream>>>(tt, Af, Bf, Cf, Df,
                                                  Ab, Bb, Cb, Db, kf, kb, nsb, hpad, copad);
  mega_prep<<<dim3(18944), dim3(256), 0, stream>>>(x, xb, Wi, wit, Wo, wot,
                                                   w1, w1t, w2, w2t, kf, kb, be1, be2, Tmat);

  // h0 = x @ Wi + bi (bf16)
  gemm8<0><<<dim3(256), dim3(512), 0, stream>>>(xb, 1024, BSTR, wit, 1024, h0, BSTR, bi, 1024, 64);
  // LN1 -> hpad
  ln1_k<<<dim3(4096), dim3(256), 0, stream>>>(h0, hpad, g1, b1);
  // Ht = transpose(h)
  trans_h<<<dim3(32, 16, 8), dim3(256), 0, stream>>>(hpad, ht);
  // fused: conv1+silu -> copad rows 1..L ; ssm -> hmixF = ns * (T @ H)
  mix8<<<dim3(512), dim3(512), 0, stream>>>(hpad, w1t, copad + 1024, bc1,
                                            Tmat, ht, nsb, hmixF);
  // conv2: hmixF += acc + bc2 (in-place)
  gemm8<2><<<dim3(256), dim3(512), 0, stream>>>(copad, 1024, PSTR, w2t, 3072, hmixF, BSTR, bc2, 3072, 64);
  // out_pre = hmixF @ Wo + bo -> h0
  gemm8<0><<<dim3(256), dim3(512), 0, stream>>>(hmixF, 1024, BSTR, wot, 1024, h0, BSTR, bo, 1024, 64);
  // out = x + LN2(out_pre)
  ln2_k<<<dim3(4096), dim3(256), 0, stream>>>(h0, x, g2, b2, (float*)d_out);
}